// Round 5
// baseline (177.966 us; speedup 1.0000x reference)
//
#include <hip/hip_runtime.h>
#include <math.h>

#define NG 800000        // = 12500 * 64
#define NTILE 12500
#define GRID 512

typedef __attribute__((ext_vector_type(8))) short short8;
typedef __attribute__((ext_vector_type(4))) float f32x4;

// LDS layout (bytes)
#define W2T_OFF 0        // 16 KB  [c=128][k=64] bf16 swz
#define W3T_OFF 16384    // 24 KB  [c=96][k=128] bf16 swz
#define WIT_OFF 40960    //  6 KB  [c=96][k=32]  bf16 swz
#define H1_OFF  47104    //  8 KB  H1 image [64][64] bf16 swz; also GPS stage (64x112B)
#define H2_OFF  55296    // 16 KB  H2 image [64][128] bf16 swz
#define AN_OFF  71680    //  4 KB  AN image [64][32] bf16 swz
#define B2_OFF  75776    // 512 B
#define BC_OFF  76288    // 384 B
#define M_OFF   76672    // 256 B  reuse mask f32[64]
#define GPM_OFF 76928    // 256 B  gp_mask f32[64]
#define LDS_TOT 77184

__device__ __forceinline__ float sis(float t) {
    t = fminf(fmaxf(t, 0.01f), 0.99f);
    return logf(t / (1.0f - t));
}
__device__ __forceinline__ unsigned short f2bf(float f) {
    unsigned int u = __float_as_uint(f);
    return (unsigned short)((u + 0x7FFFu + ((u >> 16) & 1u)) >> 16);
}
__device__ __forceinline__ unsigned int cvtpk(float a, float b) {
    unsigned int r;
    asm("v_cvt_pk_bf16_f32 %0, %1, %2" : "=v"(r) : "v"(a), "v"(b));
    return r;
}
__device__ __forceinline__ void gload16(const void* g, void* l) {
    __builtin_amdgcn_global_load_lds(
        (const __attribute__((address_space(1))) void*)g,
        (__attribute__((address_space(3))) void*)l,
        16, 0, 0);
}
#define LBAR() do { asm volatile("s_waitcnt lgkmcnt(0)" ::: "memory"); \
                    __builtin_amdgcn_s_barrier(); } while (0)

// Stage one 64-row gp tile into the H1 region as 112B-padded rows.
// LDS dest is linear (wave-uniform base + lane*16); the SOURCE is pre-swizzled:
// lds byte o -> row=o/112, cc=o%112; src byte = row*100 + (cc<96 ? cc : 84).
// (chunk 6 re-reads bytes 84..99, so col 24 sits at q6.w; never OOB.)
__device__ __forceinline__ void stage_gps(const float* gp, int tile, int t, char* lds) {
    const char* base = (const char*)gp + (long)tile * 6400;
    int wv = t >> 6, lane = t & 63;
    {
        int o = wv * 1024 + lane * 16;
        int row = o / 112;
        int cc = o - row * 112;
        int src = row * 100 + (cc < 96 ? cc : 84);
        gload16(base + src, lds + H1_OFF + wv * 1024);
    }
    if (wv < 3) {
        int o = 4096 + wv * 1024 + lane * 16;
        int row = o / 112;
        int cc = o - row * 112;
        int src = row * 100 + (cc < 96 ? cc : 84);
        gload16(base + src, lds + H1_OFF + 4096 + wv * 1024);
    }
}

__global__ __launch_bounds__(256, 2) void k_fused(
    const float* __restrict__ gp,
    const float* __restrict__ zbuf,
    const float* __restrict__ w2c,
    const float* __restrict__ ck,
    const float* __restrict__ vo,
    const float* __restrict__ ss,
    const float* __restrict__ cvr,
    const float* __restrict__ W1, const float* __restrict__ b1,
    const float* __restrict__ W2, const float* __restrict__ b2,
    const float* __restrict__ W3, const float* __restrict__ b3,
    const float* __restrict__ Wi, const float* __restrict__ bi,
    float* __restrict__ oA, float* __restrict__ oT,
    float* __restrict__ oI, float* __restrict__ oP, float* __restrict__ oM)
{
    __shared__ __align__(16) char lds[LDS_TOT];
    float* sB2 = (float*)(lds + B2_OFF);
    float* sBC = (float*)(lds + BC_OFF);
    float* sM  = (float*)(lds + M_OFF);
    float* sGP = (float*)(lds + GPM_OFF);

    const int t  = threadIdx.x;
    const int wv = t >> 6;
    const int l  = t & 63;
    const int la = l & 15;
    const int lb = l >> 4;
    const int rB = wv * 16 + la;
    const int r  = t >> 2;      // geometry row 0..63
    const int sub = t & 3;      // quad id

    // ---- initial gp stage (async) + weight images ----
    stage_gps(gp, blockIdx.x, t, lds);

    for (int idx = t; idx < 8192; idx += 256) {
        int k = idx >> 7, c = idx & 127;
        *(unsigned short*)(lds + W2T_OFF + c*128 + (((k>>3) ^ (c&7))<<4) + (k&7)*2)
            = f2bf(W2[idx]);
    }
    for (int idx = t; idx < 12288; idx += 256) {
        int k = idx / 96, c = idx - k*96;
        *(unsigned short*)(lds + W3T_OFF + c*256 + (((k>>3) ^ (c&15))<<4) + (k&7)*2)
            = f2bf(W3[idx]);
    }
    for (int idx = t; idx < 3072; idx += 256) {
        int c = idx >> 5, k = idx & 31;
        float val = (k < 23) ? Wi[k*96 + c] : 0.0f;
        *(unsigned short*)(lds + WIT_OFF + c*64 + (((k>>3) ^ (c&3))<<4) + (k&7)*2)
            = f2bf(val);
    }
    if (t < 128) sB2[t] = b2[t];
    if (t < 96)  sBC[t] = b3[t] + bi[t];

    // W1/b1 columns for this sub's 16-col block, in registers
    float4 w1a[4], w1b[4], b1r[4];
    #pragma unroll
    for (int gi = 0; gi < 4; ++gi) {
        w1a[gi] = *(const float4*)&W1[sub*16 + gi*4];
        w1b[gi] = *(const float4*)&W1[64 + sub*16 + gi*4];
        b1r[gi] = *(const float4*)&b1[sub*16 + gi*4];
    }

    // uniforms
    const float R00=w2c[0],R01=w2c[1],R02=w2c[2],T0=w2c[3];
    const float R10=w2c[4],R11=w2c[5],R12=w2c[6],T1=w2c[7];
    const float R20=w2c[8],R21=w2c[9],R22=w2c[10],T2=w2c[11];
    const float k00=ck[0],k02=ck[2],k11=ck[4],k12=ck[5];
    const float n0=vo[0]+1e-3f, n1=vo[1]+1e-3f, n2=vo[2]+1e-3f;
    const float f0=vo[0]+ss[0]-1e-3f, f1=vo[1]+ss[1]-1e-3f, f2=vo[2]+ss[2]-1e-3f;
    const float cv0=cvr[0],cv1=cvr[1],cv2=cvr[2],cv3=cvr[3],cv4=cvr[4],cv5=cvr[5];
    const float i30=1.0f/(cv3-cv0), i41=1.0f/(cv4-cv1), i52=1.0f/(cv5-cv2);
    // w2c quaternion (uniform)
    const float qtr = R00 + R11 + R22;
    const float qw = sqrtf(fmaxf(qtr + 1.0f, 1e-8f)) * 0.5f;
    const float qi4 = 0.25f / qw;
    const float qx = (R21-R12)*qi4, qy=(R02-R20)*qi4, qz=(R10-R01)*qi4;

    __syncthreads();   // weights + initial GPS visible

    for (int tile = blockIdx.x; tile < NTILE; tile += GRID) {
        const long R0 = (long)tile * 64;

        // ================= G part 1: read row, geometry =================
        const char* GPSr = lds + H1_OFF + r*112;
        float4 q0 = *(const float4*)(GPSr);
        float4 q1 = *(const float4*)(GPSr+16);
        float4 q2v= *(const float4*)(GPSr+32);
        float4 q3 = *(const float4*)(GPSr+48);
        float4 q4 = *(const float4*)(GPSr+64);
        float4 q5 = *(const float4*)(GPSr+80);
        float4 q6 = *(const float4*)(GPSr+96);   // = cols 21,22,23,24

        const float x=q0.x, y=q0.y, zz=q0.z;
        const float c0 = R00*x + R01*y + R02*zz + T0;
        const float c1 = R10*x + R11*y + R12*zz + T1;
        const float c2 = R20*x + R21*y + R22*zz + T2;

        bool m1 = c2 > 1e-6f;
        float zc = m1 ? c2 : 1e-6f;
        float fpx = k00 * c0 / zc + k02;
        float fpy = k11 * c1 / zc + k12;
        bool m2 = (fpx >= 0.f) && (fpx < 640.f) && (fpy >= 0.f) && (fpy < 480.f);
        bool mall = m1 && m2;
        bool gpm = (x>n0)&&(x<f0)&&(y>n1)&&(y<f1)&&(zz>n2)&&(zz<f2);
        bool mdet = mall && gpm;
        float tag = (q5.w == 1.0f) ? 0.5f : 0.0f;
        if (!mdet) tag = 1.0f;
        bool gm = (c0>=cv0)&&(c0<=cv3)&&(c1>=cv1)&&(c1<=cv4)&&(c2>=cv2)&&(c2<=cv5);
        bool reuse = gpm && gm;

        if (sub == 0) {
            sGP[r] = gpm ? 1.0f : 0.0f;
            sM[r]  = reuse ? 1.0f : 0.0f;
            oM[R0 + r] = reuse ? 1.0f : 0.0f;
            oT[R0 + r] = reuse ? tag : 0.0f;
        }

        // df (fp32): z-gather + depth_real
        float czs = (fabsf(c2) < 1e-6f) ? 1e-6f : c2;
        float px = k00*c0/czs + k02;
        float py = k11*c1/czs + k12;
        int ix = (int)fminf(fmaxf(px, 0.f), 639.f);
        int iy = (int)fminf(fmaxf(py, 0.f), 479.f);
        float d0 = zbuf[iy*640 + ix];
        float d1 = c2;

        // anchor (fp32, zero if !reuse)
        float ar[23];
        if (reuse) {
            float p0=q1.z, p1=q1.w, p2=q2v.x, p3=q2v.y;
            ar[0] = sis((c0 - cv0) * i30);
            ar[1] = sis((c1 - cv1) * i41);
            ar[2] = sis((c2 - cv2) * i52);
            ar[3] = sis(q0.w); ar[4] = sis(q1.x); ar[5] = sis(q1.y);
            ar[6] = qw*p0 - qx*p1 - qy*p2 - qz*p3;
            ar[7] = qw*p1 + qx*p0 + qy*p3 - qz*p2;
            ar[8] = qw*p2 - qx*p3 + qy*p0 + qz*p1;
            ar[9] = qw*p3 + qx*p2 - qy*p1 + qz*p0;
            ar[10] = sis(q2v.z);
            ar[11]=q2v.w; ar[12]=q3.x; ar[13]=q3.y; ar[14]=q3.z; ar[15]=q3.w;
            ar[16]=q4.x; ar[17]=q4.y; ar[18]=q4.z; ar[19]=q4.w;
            ar[20]=q5.x; ar[21]=q5.y; ar[22]=q5.z;
        } else {
            #pragma unroll
            for (int j = 0; j < 23; ++j) ar[j] = 0.0f;
        }

        LBAR();   // sGP/sM visible; all GPS reads done

        // ================= G part 2: outputs + H1/AN images =============
        // oA (fp32) + AN bf16 granule, constant indices per sub
        {
            float* oArow = oA + (R0 + r) * 23;
            uint4 anp;
            if (sub == 0) {
                oArow[0]=ar[0]; oArow[1]=ar[1]; oArow[2]=ar[2];
                oArow[3]=ar[3]; oArow[4]=ar[4]; oArow[5]=ar[5];
                anp.x=cvtpk(ar[0],ar[1]); anp.y=cvtpk(ar[2],ar[3]);
                anp.z=cvtpk(ar[4],ar[5]); anp.w=cvtpk(ar[6],ar[7]);
            } else if (sub == 1) {
                oArow[6]=ar[6]; oArow[7]=ar[7]; oArow[8]=ar[8];
                oArow[9]=ar[9]; oArow[10]=ar[10]; oArow[11]=ar[11];
                anp.x=cvtpk(ar[8],ar[9]);  anp.y=cvtpk(ar[10],ar[11]);
                anp.z=cvtpk(ar[12],ar[13]); anp.w=cvtpk(ar[14],ar[15]);
            } else if (sub == 2) {
                oArow[12]=ar[12]; oArow[13]=ar[13]; oArow[14]=ar[14];
                oArow[15]=ar[15]; oArow[16]=ar[16]; oArow[17]=ar[17];
                anp.x=cvtpk(ar[16],ar[17]); anp.y=cvtpk(ar[18],ar[19]);
                anp.z=cvtpk(ar[20],ar[21]); anp.w=cvtpk(ar[22],0.0f);
            } else {
                oArow[18]=ar[18]; oArow[19]=ar[19]; oArow[20]=ar[20];
                oArow[21]=ar[21]; oArow[22]=ar[22];
                anp.x=0u; anp.y=0u; anp.z=0u; anp.w=0u;
            }
            *(uint4*)(lds + AN_OFF + r*64 + ((sub ^ (r&3))<<4)) = anp;
        }
        // H1: this sub's 16 cols
        {
            float h[16];
            #pragma unroll
            for (int gi = 0; gi < 4; ++gi) {
                h[gi*4+0] = fmaxf(fmaf(d0, w1a[gi].x, fmaf(d1, w1b[gi].x, b1r[gi].x)), 0.f);
                h[gi*4+1] = fmaxf(fmaf(d0, w1a[gi].y, fmaf(d1, w1b[gi].y, b1r[gi].y)), 0.f);
                h[gi*4+2] = fmaxf(fmaf(d0, w1a[gi].z, fmaf(d1, w1b[gi].z, b1r[gi].z)), 0.f);
                h[gi*4+3] = fmaxf(fmaf(d0, w1a[gi].w, fmaf(d1, w1b[gi].w, b1r[gi].w)), 0.f);
            }
            uint4 pa, pb;
            pa.x = cvtpk(h[0],h[1]);  pa.y = cvtpk(h[2],h[3]);
            pa.z = cvtpk(h[4],h[5]);  pa.w = cvtpk(h[6],h[7]);
            pb.x = cvtpk(h[8],h[9]);  pb.y = cvtpk(h[10],h[11]);
            pb.z = cvtpk(h[12],h[13]); pb.w = cvtpk(h[14],h[15]);
            int pg0 = (2*sub)     ^ (r & 7);
            int pg1 = (2*sub + 1) ^ (r & 7);
            *(uint4*)(lds + H1_OFF + r*128 + (pg0<<4)) = pa;
            *(uint4*)(lds + H1_OFF + r*128 + (pg1<<4)) = pb;
        }
        // oP copy: gp (L2-hot) -> oP with col-24 patch from sGP
        #pragma unroll
        for (int s2 = 0; s2 < 2; ++s2) {
            int k = t + s2*256;
            if (k < 400) {
                float4 pv = *(const float4*)(gp + R0*25 + k*4);
                int e = k*4;
                #pragma unroll
                for (int j = 0; j < 4; ++j) {
                    int ej = e + j;
                    int rowj = ej / 25;
                    if (ej - rowj*25 == 24) {
                        float gv = sGP[rowj];
                        float ov = (j==0) ? pv.x : (j==1) ? pv.y : (j==2) ? pv.z : pv.w;
                        float nv = (gv != 0.f) ? 1.0f : ov;
                        if (j==0) pv.x=nv; else if (j==1) pv.y=nv;
                        else if (j==2) pv.z=nv; else pv.w=nv;
                    }
                }
                *(float4*)(oP + R0*25 + k*4) = pv;
            }
        }

        LBAR();   // H1/AN images ready

        // ================= M1: GEMM1 =================
        {
            short8 hb0 = *(short8*)(lds + H1_OFF + rB*128 + (((lb  ) ^ (rB&7))<<4));
            short8 hb1 = *(short8*)(lds + H1_OFF + rB*128 + (((lb+4) ^ (rB&7))<<4));
            #pragma unroll
            for (int ct = 0; ct < 8; ++ct) {
                const int c = ct*16 + la;
                short8 a0 = *(short8*)(lds + W2T_OFF + c*128 + (((lb  ) ^ (c&7))<<4));
                short8 a1 = *(short8*)(lds + W2T_OFF + c*128 + (((lb+4) ^ (c&7))<<4));
                f32x4 acc = {0.f, 0.f, 0.f, 0.f};
                acc = __builtin_amdgcn_mfma_f32_16x16x32_bf16(a0, hb0, acc, 0, 0, 0);
                acc = __builtin_amdgcn_mfma_f32_16x16x32_bf16(a1, hb1, acc, 0, 0, 0);
                float4 bb = *(float4*)&sB2[ct*16 + lb*4];
                float e0 = fmaxf(acc[0] + bb.x, 0.f);
                float e1 = fmaxf(acc[1] + bb.y, 0.f);
                float e2 = fmaxf(acc[2] + bb.z, 0.f);
                float e3 = fmaxf(acc[3] + bb.w, 0.f);
                uint2 pk; pk.x = cvtpk(e0, e1); pk.y = cvtpk(e2, e3);
                const int g = ct*2 + (lb>>1);
                *(uint2*)(lds + H2_OFF + rB*256 + ((g ^ (rB&15))<<4) + (lb&1)*8) = pk;
            }
        }

        LBAR();   // H2 ready

        // ================= M2: stage next tile + GEMM2 =================
        if (tile + GRID < NTILE) stage_gps(gp, tile + GRID, t, lds);
        {
            short8 B0 = *(short8*)(lds + H2_OFF + rB*256 + ((( 0 + lb) ^ (rB&15))<<4));
            short8 B1 = *(short8*)(lds + H2_OFF + rB*256 + ((( 4 + lb) ^ (rB&15))<<4));
            short8 B2v= *(short8*)(lds + H2_OFF + rB*256 + ((( 8 + lb) ^ (rB&15))<<4));
            short8 B3 = *(short8*)(lds + H2_OFF + rB*256 + (((12 + lb) ^ (rB&15))<<4));
            short8 bA = *(short8*)(lds + AN_OFF + rB*64 + ((lb ^ (rB&3))<<4));
            float mk2 = sM[rB];
            float* orow = oI + (R0 + rB) * 96;
            #pragma unroll
            for (int ct = 0; ct < 6; ++ct) {
                const int c = ct*16 + la;
                f32x4 acc = {0.f, 0.f, 0.f, 0.f};
                short8 A0 = *(short8*)(lds + W3T_OFF + c*256 + ((( 0 + lb) ^ (c&15))<<4));
                short8 A1 = *(short8*)(lds + W3T_OFF + c*256 + ((( 4 + lb) ^ (c&15))<<4));
                short8 A2 = *(short8*)(lds + W3T_OFF + c*256 + ((( 8 + lb) ^ (c&15))<<4));
                short8 A3 = *(short8*)(lds + W3T_OFF + c*256 + (((12 + lb) ^ (c&15))<<4));
                acc = __builtin_amdgcn_mfma_f32_16x16x32_bf16(A0, B0, acc, 0, 0, 0);
                acc = __builtin_amdgcn_mfma_f32_16x16x32_bf16(A1, B1, acc, 0, 0, 0);
                acc = __builtin_amdgcn_mfma_f32_16x16x32_bf16(A2, B2v, acc, 0, 0, 0);
                acc = __builtin_amdgcn_mfma_f32_16x16x32_bf16(A3, B3, acc, 0, 0, 0);
                short8 Aw = *(short8*)(lds + WIT_OFF + c*64 + ((lb ^ (c&3))<<4));
                acc = __builtin_amdgcn_mfma_f32_16x16x32_bf16(Aw, bA, acc, 0, 0, 0);
                float4 bb = *(float4*)&sBC[ct*16 + lb*4];
                float4 o;
                o.x = (mk2 != 0.f) ? acc[0] + bb.x : 0.f;
                o.y = (mk2 != 0.f) ? acc[1] + bb.y : 0.f;
                o.z = (mk2 != 0.f) ? acc[2] + bb.z : 0.f;
                o.w = (mk2 != 0.f) ? acc[3] + bb.w : 0.f;
                *(float4*)(orow + ct*16 + lb*4) = o;
            }
        }

        __syncthreads();   // drains vmcnt (GPS loads + stores) + lgkm
    }
}

extern "C" void kernel_launch(void* const* d_in, const int* in_sizes, int n_in,
                              void* d_out, int out_size, void* d_ws, size_t ws_size,
                              hipStream_t stream)
{
    const float* gp  = (const float*)d_in[0];
    const float* zb  = (const float*)d_in[2];
    const float* w2c = (const float*)d_in[3];
    const float* ck  = (const float*)d_in[4];
    const float* vo  = (const float*)d_in[5];
    const float* ss  = (const float*)d_in[6];
    const float* cvr = (const float*)d_in[7];
    const float* Wi  = (const float*)d_in[8];
    const float* bi  = (const float*)d_in[9];
    const float* W1  = (const float*)d_in[10];
    const float* b1  = (const float*)d_in[11];
    const float* W2  = (const float*)d_in[12];
    const float* b2  = (const float*)d_in[13];
    const float* W3  = (const float*)d_in[14];
    const float* b3  = (const float*)d_in[15];

    float* out = (float*)d_out;
    const long N = NG;
    float* oA = out;               // (N,23)
    float* oT = out + 23L * N;     // (N,)
    float* oI = out + 24L * N;     // (N,96)
    float* oP = out + 120L * N;    // (N,25)
    float* oM = out + 145L * N;    // (N,)

    k_fused<<<GRID, 256, 0, stream>>>(gp, zb, w2c, ck, vo, ss, cvr,
                                      W1, b1, W2, b2, W3, b3, Wi, bi,
                                      oA, oT, oI, oP, oM);
}

// Round 6
// 172.835 us; speedup vs baseline: 1.0297x; 1.0297x over previous
//
#include <hip/hip_runtime.h>
#include <math.h>

#define NG 800000        // = 12500 chunks of 64 rows
#define NCH 12500
#define GRID 256
#define BLK 512
#define WPB 8

typedef __attribute__((ext_vector_type(8))) short short8;
typedef __attribute__((ext_vector_type(4))) float f32x4;

// ---- shared LDS layout (bytes) ----
#define W2T_OFF 0        // 16384  [c=128][k=64] bf16 swz
#define W3T_OFF 16384    // 24576  [c=96][k=128] bf16 swz
#define WIT_OFF 40960    //  6144  [c=96][k=32]  bf16 swz
#define B2_OFF  47104    //   512  f32[128]
#define BC_OFF  47616    //   384  f32[96]
#define WV_OFF  48128    // per-wave regions
// per-wave region (11008 B):
#define H1S  0           //  2048  [16][64]  bf16 swz (strip)
#define H2S  2048        //  4096  [16][128] bf16 swz (strip)
#define ANB  6144        //  4096  [64][32]  bf16 swz
#define DFP  10240       //   512  float2[64]
#define SMK  10752       //   256  float[64]
#define WV_SZ 11008
#define LDS_TOT (WV_OFF + WPB * WV_SZ)   // 136192

__device__ __forceinline__ float sis(float t) {
    t = fminf(fmaxf(t, 0.01f), 0.99f);
    return logf(t / (1.0f - t));
}
__device__ __forceinline__ unsigned short f2bf(float f) {
    unsigned int u = __float_as_uint(f);
    return (unsigned short)((u + 0x7FFFu + ((u >> 16) & 1u)) >> 16);
}
__device__ __forceinline__ unsigned int cvtpk(float a, float b) {
    unsigned int r;
    asm("v_cvt_pk_bf16_f32 %0, %1, %2" : "=v"(r) : "v"(a), "v"(b));
    return r;
}

__global__ __launch_bounds__(BLK, 2) void k_main(
    const float* __restrict__ gp,
    const float* __restrict__ zbuf,
    const float* __restrict__ w2c,
    const float* __restrict__ ck,
    const float* __restrict__ vo,
    const float* __restrict__ ss,
    const float* __restrict__ cvr,
    const float* __restrict__ W1, const float* __restrict__ b1,
    const float* __restrict__ W2, const float* __restrict__ b2,
    const float* __restrict__ W3, const float* __restrict__ b3,
    const float* __restrict__ Wi, const float* __restrict__ bi,
    float* __restrict__ oA, float* __restrict__ oT,
    float* __restrict__ oI, float* __restrict__ oP, float* __restrict__ oM)
{
    __shared__ __align__(16) char lds[LDS_TOT];
    float* sB2 = (float*)(lds + B2_OFF);
    float* sBC = (float*)(lds + BC_OFF);

    const int t   = threadIdx.x;
    const int wv  = t >> 6;
    const int l   = t & 63;
    const int la  = l & 15;
    const int lb  = l >> 4;
    const int sub = l & 3;
    char* wlds = lds + WV_OFF + wv * WV_SZ;
    float2* dfp = (float2*)(wlds + DFP);
    float*  smk = (float*)(wlds + SMK);

    // ---- build shared weight images (once per block) ----
    for (int idx = t; idx < 8192; idx += BLK) {            // W2T
        int k = idx >> 7, c = idx & 127;
        *(unsigned short*)(lds + W2T_OFF + c*128 + (((k>>3) ^ (c&7))<<4) + (k&7)*2)
            = f2bf(W2[idx]);
    }
    for (int idx = t; idx < 12288; idx += BLK) {           // W3T
        int k = idx / 96, c = idx - k*96;
        *(unsigned short*)(lds + W3T_OFF + c*256 + (((k>>3) ^ (c&15))<<4) + (k&7)*2)
            = f2bf(W3[idx]);
    }
    for (int idx = t; idx < 3072; idx += BLK) {            // WIT
        int c = idx >> 5, k = idx & 31;
        float val = (k < 23) ? Wi[k*96 + c] : 0.0f;
        *(unsigned short*)(lds + WIT_OFF + c*64 + (((k>>3) ^ (c&3))<<4) + (k&7)*2)
            = f2bf(val);
    }
    if (t < 128) sB2[t] = b2[t];
    if (t < 96)  sBC[t] = b3[t] + bi[t];

    // per-lane W1/b1 column block (cols sub*16..sub*16+15) in registers
    float4 w1a[4], w1b[4], b1r[4];
    #pragma unroll
    for (int gi = 0; gi < 4; ++gi) {
        w1a[gi] = *(const float4*)&W1[sub*16 + gi*4];
        w1b[gi] = *(const float4*)&W1[64 + sub*16 + gi*4];
        b1r[gi] = *(const float4*)&b1[sub*16 + gi*4];
    }

    // uniforms
    const float R00=w2c[0],R01=w2c[1],R02=w2c[2],T0=w2c[3];
    const float R10=w2c[4],R11=w2c[5],R12=w2c[6],T1=w2c[7];
    const float R20=w2c[8],R21=w2c[9],R22=w2c[10],T2=w2c[11];
    const float k00=ck[0],k02=ck[2],k11=ck[4],k12=ck[5];
    const float n0=vo[0]+1e-3f, n1=vo[1]+1e-3f, n2=vo[2]+1e-3f;
    const float f0=vo[0]+ss[0]-1e-3f, f1=vo[1]+ss[1]-1e-3f, f2=vo[2]+ss[2]-1e-3f;
    const float cv0=cvr[0],cv1=cvr[1],cv2=cvr[2],cv3=cvr[3],cv4=cvr[4],cv5=cvr[5];
    const float i30=1.0f/(cv3-cv0), i41=1.0f/(cv4-cv1), i52=1.0f/(cv5-cv2);
    const float qtr = R00 + R11 + R22;
    const float qw = sqrtf(fmaxf(qtr + 1.0f, 1e-8f)) * 0.5f;
    const float qi4 = 0.25f / qw;
    const float qx = (R21-R12)*qi4, qy=(R02-R20)*qi4, qz=(R10-R01)*qi4;

    __syncthreads();   // weight images visible; ONLY barrier in the kernel

    // ---- per-wave free-running loop over 64-row chunks ----
    for (int c = blockIdx.x * WPB + wv; c < NCH; c += GRID * WPB) {
        const long Rb = (long)c * 64;
        const long R  = Rb + l;

        // -- load own row (25 scalars) --
        const float* g = gp + R * 25;
        float v[25];
        #pragma unroll
        for (int j = 0; j < 25; ++j) v[j] = g[j];

        // -- geometry --
        const float x=v[0], y=v[1], zz=v[2];
        const float c0 = R00*x + R01*y + R02*zz + T0;
        const float c1 = R10*x + R11*y + R12*zz + T1;
        const float c2 = R20*x + R21*y + R22*zz + T2;

        bool m1 = c2 > 1e-6f;
        float zc = m1 ? c2 : 1e-6f;
        float fpx = k00 * c0 / zc + k02;
        float fpy = k11 * c1 / zc + k12;
        bool m2 = (fpx >= 0.f) && (fpx < 640.f) && (fpy >= 0.f) && (fpy < 480.f);
        bool mall = m1 && m2;
        bool gpm = (x>n0)&&(x<f0)&&(y>n1)&&(y<f1)&&(zz>n2)&&(zz<f2);
        bool mdet = mall && gpm;
        float tag = (v[23] == 1.0f) ? 0.5f : 0.0f;
        if (!mdet) tag = 1.0f;
        bool gm = (c0>=cv0)&&(c0<=cv3)&&(c1>=cv1)&&(c1<=cv4)&&(c2>=cv2)&&(c2<=cv5);
        bool reuse = gpm && gm;

        oM[R] = reuse ? 1.0f : 0.0f;
        oT[R] = reuse ? tag : 0.0f;
        smk[l] = reuse ? 1.0f : 0.0f;

        // df (fp32)
        float czs = (fabsf(c2) < 1e-6f) ? 1e-6f : c2;
        float px = k00*c0/czs + k02;
        float py = k11*c1/czs + k12;
        int ix = (int)fminf(fmaxf(px, 0.f), 639.f);
        int iy = (int)fminf(fmaxf(py, 0.f), 479.f);
        float d0g = zbuf[iy*640 + ix];
        dfp[l] = make_float2(d0g, c2);

        // anchor
        float ar[23];
        if (reuse) {
            float p0=v[6], p1=v[7], p2=v[8], p3=v[9];
            ar[0] = sis((c0 - cv0) * i30);
            ar[1] = sis((c1 - cv1) * i41);
            ar[2] = sis((c2 - cv2) * i52);
            ar[3] = sis(v[3]); ar[4] = sis(v[4]); ar[5] = sis(v[5]);
            ar[6] = qw*p0 - qx*p1 - qy*p2 - qz*p3;
            ar[7] = qw*p1 + qx*p0 + qy*p3 - qz*p2;
            ar[8] = qw*p2 - qx*p3 + qy*p0 + qz*p1;
            ar[9] = qw*p3 + qx*p2 - qy*p1 + qz*p0;
            ar[10] = sis(v[10]);
            #pragma unroll
            for (int j = 0; j < 12; ++j) ar[11+j] = v[11+j];
        } else {
            #pragma unroll
            for (int j = 0; j < 23; ++j) ar[j] = 0.0f;
        }

        // oA / oP stores (fire-and-forget, scalar, line-dense)
        {
            float* oArow = oA + R * 23;
            #pragma unroll
            for (int j = 0; j < 23; ++j) oArow[j] = ar[j];
            float* oProw = oP + R * 25;
            #pragma unroll
            for (int j = 0; j < 24; ++j) oProw[j] = v[j];
            oProw[24] = gpm ? 1.0f : v[24];
        }

        // AN image: own row l, 32 cols bf16 (23 real)
        {
            uint4 a0, a1, a2, a3;
            a0.x=cvtpk(ar[0],ar[1]);   a0.y=cvtpk(ar[2],ar[3]);
            a0.z=cvtpk(ar[4],ar[5]);   a0.w=cvtpk(ar[6],ar[7]);
            a1.x=cvtpk(ar[8],ar[9]);   a1.y=cvtpk(ar[10],ar[11]);
            a1.z=cvtpk(ar[12],ar[13]); a1.w=cvtpk(ar[14],ar[15]);
            a2.x=cvtpk(ar[16],ar[17]); a2.y=cvtpk(ar[18],ar[19]);
            a2.z=cvtpk(ar[20],ar[21]); a2.w=cvtpk(ar[22],0.0f);
            a3.x=0u; a3.y=0u; a3.z=0u; a3.w=0u;
            char* anr = wlds + ANB + l*64;
            *(uint4*)(anr + ((0 ^ (l&3))<<4)) = a0;
            *(uint4*)(anr + ((1 ^ (l&3))<<4)) = a1;
            *(uint4*)(anr + ((2 ^ (l&3))<<4)) = a2;
            *(uint4*)(anr + ((3 ^ (l&3))<<4)) = a3;
        }

        // ---- 4 strips of 16 rows: H1 -> GEMM1 -> GEMM2 ----
        for (int s = 0; s < 4; ++s) {
            // H1 strip: lane computes row (l>>2)'s cols sub*16..+15
            {
                const int rr = l >> 2;
                float2 dfv = dfp[16*s + rr];
                float h[16];
                #pragma unroll
                for (int gi = 0; gi < 4; ++gi) {
                    h[gi*4+0] = fmaxf(fmaf(dfv.x, w1a[gi].x, fmaf(dfv.y, w1b[gi].x, b1r[gi].x)), 0.f);
                    h[gi*4+1] = fmaxf(fmaf(dfv.x, w1a[gi].y, fmaf(dfv.y, w1b[gi].y, b1r[gi].y)), 0.f);
                    h[gi*4+2] = fmaxf(fmaf(dfv.x, w1a[gi].z, fmaf(dfv.y, w1b[gi].z, b1r[gi].z)), 0.f);
                    h[gi*4+3] = fmaxf(fmaf(dfv.x, w1a[gi].w, fmaf(dfv.y, w1b[gi].w, b1r[gi].w)), 0.f);
                }
                uint4 pa, pb;
                pa.x = cvtpk(h[0],h[1]);   pa.y = cvtpk(h[2],h[3]);
                pa.z = cvtpk(h[4],h[5]);   pa.w = cvtpk(h[6],h[7]);
                pb.x = cvtpk(h[8],h[9]);   pb.y = cvtpk(h[10],h[11]);
                pb.z = cvtpk(h[12],h[13]); pb.w = cvtpk(h[14],h[15]);
                char* h1r = wlds + H1S + rr*128;
                *(uint4*)(h1r + (((2*sub  ) ^ (rr&7))<<4)) = pa;
                *(uint4*)(h1r + (((2*sub+1) ^ (rr&7))<<4)) = pb;
            }

            // GEMM1: H2s[la][128] = relu(H1s[la] @ W2 + b2)
            {
                short8 hb0 = *(short8*)(wlds + H1S + la*128 + (((lb  ) ^ (la&7))<<4));
                short8 hb1 = *(short8*)(wlds + H1S + la*128 + (((lb+4) ^ (la&7))<<4));
                #pragma unroll
                for (int ct = 0; ct < 8; ++ct) {
                    const int cc = ct*16 + la;
                    short8 a0 = *(short8*)(lds + W2T_OFF + cc*128 + (((lb  ) ^ (cc&7))<<4));
                    short8 a1 = *(short8*)(lds + W2T_OFF + cc*128 + (((lb+4) ^ (cc&7))<<4));
                    f32x4 acc = {0.f, 0.f, 0.f, 0.f};
                    acc = __builtin_amdgcn_mfma_f32_16x16x32_bf16(a0, hb0, acc, 0, 0, 0);
                    acc = __builtin_amdgcn_mfma_f32_16x16x32_bf16(a1, hb1, acc, 0, 0, 0);
                    float4 bb = *(float4*)&sB2[ct*16 + lb*4];
                    float e0 = fmaxf(acc[0] + bb.x, 0.f);
                    float e1 = fmaxf(acc[1] + bb.y, 0.f);
                    float e2 = fmaxf(acc[2] + bb.z, 0.f);
                    float e3 = fmaxf(acc[3] + bb.w, 0.f);
                    uint2 pk; pk.x = cvtpk(e0, e1); pk.y = cvtpk(e2, e3);
                    const int gg = ct*2 + (lb>>1);
                    *(uint2*)(wlds + H2S + la*256 + ((gg ^ la)<<4) + (lb&1)*8) = pk;
                }
            }

            // GEMM2: oI rows 16s+la = H2s @ W3 + AN @ Wi + bc, masked
            {
                short8 B0 = *(short8*)(wlds + H2S + la*256 + ((( 0 + lb) ^ la)<<4));
                short8 B1 = *(short8*)(wlds + H2S + la*256 + ((( 4 + lb) ^ la)<<4));
                short8 B2v= *(short8*)(wlds + H2S + la*256 + ((( 8 + lb) ^ la)<<4));
                short8 B3 = *(short8*)(wlds + H2S + la*256 + (((12 + lb) ^ la)<<4));
                const int row = 16*s + la;
                short8 bA = *(short8*)(wlds + ANB + row*64 + ((lb ^ (row&3))<<4));
                float mk = smk[row];
                float* orow = oI + (Rb + row) * 96;
                #pragma unroll
                for (int ct = 0; ct < 6; ++ct) {
                    const int cc = ct*16 + la;
                    f32x4 acc = {0.f, 0.f, 0.f, 0.f};
                    short8 A0 = *(short8*)(lds + W3T_OFF + cc*256 + ((( 0 + lb) ^ (cc&15))<<4));
                    short8 A1 = *(short8*)(lds + W3T_OFF + cc*256 + ((( 4 + lb) ^ (cc&15))<<4));
                    short8 A2 = *(short8*)(lds + W3T_OFF + cc*256 + ((( 8 + lb) ^ (cc&15))<<4));
                    short8 A3 = *(short8*)(lds + W3T_OFF + cc*256 + (((12 + lb) ^ (cc&15))<<4));
                    acc = __builtin_amdgcn_mfma_f32_16x16x32_bf16(A0, B0, acc, 0, 0, 0);
                    acc = __builtin_amdgcn_mfma_f32_16x16x32_bf16(A1, B1, acc, 0, 0, 0);
                    acc = __builtin_amdgcn_mfma_f32_16x16x32_bf16(A2, B2v, acc, 0, 0, 0);
                    acc = __builtin_amdgcn_mfma_f32_16x16x32_bf16(A3, B3, acc, 0, 0, 0);
                    short8 Aw = *(short8*)(lds + WIT_OFF + cc*64 + ((lb ^ (cc&3))<<4));
                    acc = __builtin_amdgcn_mfma_f32_16x16x32_bf16(Aw, bA, acc, 0, 0, 0);
                    float4 bb = *(float4*)&sBC[ct*16 + lb*4];
                    float4 o;
                    o.x = (mk != 0.f) ? acc[0] + bb.x : 0.f;
                    o.y = (mk != 0.f) ? acc[1] + bb.y : 0.f;
                    o.z = (mk != 0.f) ? acc[2] + bb.z : 0.f;
                    o.w = (mk != 0.f) ? acc[3] + bb.w : 0.f;
                    *(float4*)(orow + ct*16 + lb*4) = o;
                }
            }
        }
    }
}

extern "C" void kernel_launch(void* const* d_in, const int* in_sizes, int n_in,
                              void* d_out, int out_size, void* d_ws, size_t ws_size,
                              hipStream_t stream)
{
    const float* gp  = (const float*)d_in[0];
    const float* zb  = (const float*)d_in[2];
    const float* w2c = (const float*)d_in[3];
    const float* ck  = (const float*)d_in[4];
    const float* vo  = (const float*)d_in[5];
    const float* ss  = (const float*)d_in[6];
    const float* cvr = (const float*)d_in[7];
    const float* Wi  = (const float*)d_in[8];
    const float* bi  = (const float*)d_in[9];
    const float* W1  = (const float*)d_in[10];
    const float* b1  = (const float*)d_in[11];
    const float* W2  = (const float*)d_in[12];
    const float* b2  = (const float*)d_in[13];
    const float* W3  = (const float*)d_in[14];
    const float* b3  = (const float*)d_in[15];

    float* out = (float*)d_out;
    const long N = NG;
    float* oA = out;               // (N,23)
    float* oT = out + 23L * N;     // (N,)
    float* oI = out + 24L * N;     // (N,96)
    float* oP = out + 120L * N;    // (N,25)
    float* oM = out + 145L * N;    // (N,)

    k_main<<<GRID, BLK, 0, stream>>>(gp, zb, w2c, ck, vo, ss, cvr,
                                     W1, b1, W2, b2, W3, b3, Wi, bi,
                                     oA, oT, oI, oP, oM);
}